// Round 3
// baseline (299.498 us; speedup 1.0000x reference)
//
#include <hip/hip_runtime.h>

#define DIM   1024
#define NH    16
#define HD    64
#define BATCH 16
#define SEQ   512
#define MROWS (BATCH*SEQ)   // 8192
#define SL2E  0.18033688011112042f   // 0.125 * log2(e)

typedef __bf16 bf16x8 __attribute__((ext_vector_type(8)));
typedef float  floatx4 __attribute__((ext_vector_type(4)));
typedef short  short4v __attribute__((ext_vector_type(4)));

static __device__ __forceinline__ unsigned short f2bf(float f) {
    union { float f; unsigned u; } v; v.f = f;
    return (unsigned short)((v.u + 0x8000u) >> 16);
}
static __device__ __forceinline__ unsigned pk2(float a, float b) {
    union { float f; unsigned u; } x, y; x.f = a; y.f = b;
    return ((x.u + 0x8000u) >> 16) | ((y.u + 0x8000u) & 0xffff0000u);
}

static __device__ __forceinline__ void glds16(const void* g, void* l) {
    __builtin_amdgcn_global_load_lds(
        (const __attribute__((address_space(1))) unsigned int*)g,
        (__attribute__((address_space(3))) unsigned int*)l, 16, 0, 0);
}

// ---------------------------------------------------------------------------
// Fused prep (unchanged, verified): [0,8192) cvt x/ctx -> bf16 ;
// [8192,12288) transpose 4 weights ; [12288,12416) RoPE cos/sin table.
// ---------------------------------------------------------------------------
__global__ __launch_bounds__(256)
void prep(const float* __restrict__ x, const float* __restrict__ ctx,
          const float* __restrict__ Wq, const float* __restrict__ Wk,
          const float* __restrict__ Wv, const float* __restrict__ Wo,
          unsigned short* __restrict__ xb, unsigned short* __restrict__ cb,
          unsigned short* __restrict__ WqT, unsigned short* __restrict__ WkT,
          unsigned short* __restrict__ WvT, unsigned short* __restrict__ WoT,
          float2* __restrict__ cstab)
{
    __shared__ float tile[32][33];
    const int blk = blockIdx.x, t = threadIdx.x;
    if (blk < 8192) {
        const float* src = (blk < 4096) ? x : ctx;
        unsigned short* dst = (blk < 4096) ? xb : cb;
        int e = ((blk & 4095) * 256 + t) * 8;
        float4 f0 = *(const float4*)&src[e];
        float4 f1 = *(const float4*)&src[e + 4];
        uint4 o = { pk2(f0.x, f0.y), pk2(f0.z, f0.w), pk2(f1.x, f1.y), pk2(f1.z, f1.w) };
        *(uint4*)&dst[e] = o;
    } else if (blk < 12288) {
        int id2 = blk - 8192;
        const float* W; unsigned short* T;
        switch (id2 >> 10) {
            case 0:  W = Wq; T = WqT; break;
            case 1:  W = Wk; T = WkT; break;
            case 2:  W = Wv; T = WvT; break;
            default: W = Wo; T = WoT; break;
        }
        int local = id2 & 1023;
        int n0 = (local & 31) * 32, k0 = (local >> 5) * 32;
        int tx = t & 31, ty = t >> 5;
        #pragma unroll
        for (int a = 0; a < 4; a++)
            tile[ty + 8 * a][tx] = W[(size_t)(k0 + ty + 8 * a) * DIM + n0 + tx];
        __syncthreads();
        #pragma unroll
        for (int a = 0; a < 4; a++)
            T[(size_t)(n0 + ty + 8 * a) * DIM + k0 + tx] = f2bf(tile[tx][ty + 8 * a]);
    } else {
        int gid = (blk - 12288) * 256 + t;   // 0 .. SEQ*HD-1
        int d = gid & (HD - 1), s = gid >> 6;
        const float C = -0.41524101186092f;  // -2*log2(10000)/64
        float f = exp2f((float)(d & 31) * C);
        float a = (float)s * f;
        cstab[gid] = make_float2(cosf(a), sinf(a));
    }
}

// ---------------------------------------------------------------------------
// GEMM v4: m201-template port. BM=BN=256, BK=64, 512 threads = 8 waves
// (2M x 4N), per-wave 128x64 output (8x4 fragments of 16x16x32, transposed
// accumulate). LDS 128 KB: A,B each double-buffered 32 KB.
// 2 K-tiles/iteration, 8 phases; each phase: {stage one 16KB unit (2 glds) ||
// ds_read this quadrant's new fragments} -> s_barrier -> lgkmcnt(0) ->
// sched_barrier -> setprio(1) -> 16 MFMA -> setprio(0) -> s_barrier.
// vmcnt(6) (= 3 units in flight) ONLY at phases 4 and 8 (T4).
// Stage units per tile u (each 16KB, 2 glds/wave):
//   U0 = A rows {0-63,128-191}   (last read Ph(C1): af half ah=0)
//   U1 = B rows {(r&63)<32}      (last read Ph(C1): b0)
//   U2 = B rows {(r&63)>=32}     (last read Ph(C2): b1)
//   U3 = A rows {64-127,192-255} (last read Ph(C3): af half ah=1)
// Stage stream (iter i computes tiles 2i,2i+1): Ph1:U3(2i+1) Ph2:U0(2i+2)
// Ph3:U1(2i+2) Ph4:U2(2i+2) Ph5:U3(2i+2) Ph6:U0(2i+3) Ph7:U1(2i+3)
// Ph8:U2(2i+3).  Every stage lands >=1 phase after its slot's last reader's
// closing barrier (WAR-safe); every tile fully certified by the vmcnt(6)+
// barrier 4 phases before its first read (RAW-safe).
// Chunk-XOR LDS swizzle identical to verified v1 (0 bank conflicts).
// ---------------------------------------------------------------------------
template<int AH>
static __device__ __forceinline__ void rdA(const unsigned short* Ab, int wm, int lane16,
                                           int co0, int co1, bf16x8 af[4][2]) {
    #pragma unroll
    for (int mi = 0; mi < 4; mi++) {
        const unsigned short* r = Ab + (wm * 128 + AH * 64 + mi * 16 + lane16) * 64;
        af[mi][0] = *(const bf16x8*)&r[co0];
        af[mi][1] = *(const bf16x8*)&r[co1];
    }
}
template<int BH>
static __device__ __forceinline__ void rdB(const unsigned short* Bb, int wn, int lane16,
                                           int co0, int co1, bf16x8 bfv[2][2]) {
    #pragma unroll
    for (int ni = 0; ni < 2; ni++) {
        const unsigned short* r = Bb + (wn * 64 + BH * 32 + ni * 16 + lane16) * 64;
        bfv[ni][0] = *(const bf16x8*)&r[co0];
        bfv[ni][1] = *(const bf16x8*)&r[co1];
    }
}
template<int AH, int BH>
static __device__ __forceinline__ void mmq(bf16x8 bfv[2][2], bf16x8 af[4][2], floatx4 acc[8][4]) {
    #pragma unroll
    for (int mi = 0; mi < 4; mi++)
        #pragma unroll
        for (int ni = 0; ni < 2; ni++) {
            floatx4 c = acc[AH * 4 + mi][BH * 2 + ni];
            c = __builtin_amdgcn_mfma_f32_16x16x32_bf16(bfv[ni][0], af[mi][0], c, 0, 0, 0);
            c = __builtin_amdgcn_mfma_f32_16x16x32_bf16(bfv[ni][1], af[mi][1], c, 0, 0, 0);
            acc[AH * 4 + mi][BH * 2 + ni] = c;
        }
}

static __device__ __forceinline__ void gemm256(
    const unsigned short* __restrict__ A, const unsigned short* __restrict__ Bt,
    int m0, int n0, unsigned short* As, unsigned short* Bs, floatx4 acc[8][4])
{
    const int t = threadIdx.x;
    const int w = t >> 6, l = t & 63;
    const int wm = w >> 2, wn = w & 3;
    const int lane16 = l & 15, quad = l >> 4;
    const int lr = l >> 3;
    const int gsw = ((l & 7) ^ lr) * 8;          // pre-swizzled source col (shorts)
    const int co0 = (quad ^ (lane16 & 7)) * 8;   // fragment chunk offset, kk=0
    const int co1 = co0 ^ 32;                    // kk=1

    #pragma unroll
    for (int i = 0; i < 8; i++)
        #pragma unroll
        for (int j = 0; j < 4; j++) acc[i][j] = (floatx4){0.f, 0.f, 0.f, 0.f};

    // per-thread source row pointers + wave-uniform LDS dest offsets
    const unsigned short *aU0[2], *bU1[2];
    int dU0[2], dU1[2];
    #pragma unroll
    for (int j = 0; j < 2; j++) {
        int uj = w * 16 + j * 8 + lr;            // unit row index (per-lane)
        int ub = w * 16 + j * 8;                 // (wave-uniform)
        int rA0  = uj + (uj & 64);               // {0-63,128-191}
        int rA0b = ub + (ub & 64);
        aU0[j] = A + (size_t)(m0 + rA0) * DIM + gsw;
        dU0[j] = rA0b * 64;
        int rB1  = ((uj >> 5) << 6) + (uj & 31); // {(r&63)<32}
        int rB1b = ((ub >> 5) << 6) + (ub & 31);
        bU1[j] = Bt + (size_t)(n0 + rB1) * DIM + gsw;
        dU1[j] = rB1b * 64;
    }
    unsigned short* Ae = As;            unsigned short* Ao = As + 16384;
    unsigned short* Be = Bs;            unsigned short* Bo = Bs + 16384;

#define STG_U0(buf, kt) { glds16(aU0[0] + (kt), (buf) + dU0[0]); \
                          glds16(aU0[1] + (kt), (buf) + dU0[1]); }
#define STG_U3(buf, kt) { glds16(aU0[0] + (size_t)64 * DIM + (kt), (buf) + dU0[0] + 4096); \
                          glds16(aU0[1] + (size_t)64 * DIM + (kt), (buf) + dU0[1] + 4096); }
#define STG_U1(buf, kt) { glds16(bU1[0] + (kt), (buf) + dU1[0]); \
                          glds16(bU1[1] + (kt), (buf) + dU1[1]); }
#define STG_U2(buf, kt) { glds16(bU1[0] + (size_t)32 * DIM + (kt), (buf) + dU1[0] + 2048); \
                          glds16(bU1[1] + (size_t)32 * DIM + (kt), (buf) + dU1[1] + 2048); }
#define BAR_MFMA(MM) \
    __builtin_amdgcn_s_barrier(); \
    asm volatile("s_waitcnt lgkmcnt(0)" ::: "memory"); \
    __builtin_amdgcn_sched_barrier(0); \
    __builtin_amdgcn_s_setprio(1); \
    MM; \
    __builtin_amdgcn_s_setprio(0); \
    __builtin_amdgcn_s_barrier();

    // prologue: tile0 (4 units) -> even bufs, tile1 U0/U1/U2 -> odd bufs
    STG_U0(Ae, 0); STG_U1(Be, 0); STG_U2(Be, 0); STG_U3(Ae, 0);
    STG_U0(Ao, 64); STG_U1(Bo, 64); STG_U2(Bo, 64);
    asm volatile("s_waitcnt vmcnt(6)" ::: "memory");   // tile0 landed, 3 units in flight
    __builtin_amdgcn_s_barrier();

    bf16x8 af[4][2], b0[2][2], b1[2][2];

    #pragma unroll 1
    for (int i = 0; i < 7; i++) {
        const int k1 = (2 * i + 1) * 64, k2 = k1 + 64, k3 = k2 + 64;
        // Ph1: compute tile 2i quadrant (0,0)
        STG_U3(Ao, k1);
        rdA<0>(Ae, wm, lane16, co0, co1, af);
        rdB<0>(Be, wn, lane16, co0, co1, b0);
        BAR_MFMA((mmq<0, 0>(b0, af, acc)));
        // Ph2: quadrant (0,1)
        STG_U0(Ae, k2);
        rdB<1>(Be, wn, lane16, co0, co1, b1);
        BAR_MFMA((mmq<0, 1>(b1, af, acc)));
        // Ph3: quadrant (1,0)
        STG_U1(Be, k2);
        rdA<1>(Ae, wm, lane16, co0, co1, af);
        BAR_MFMA((mmq<1, 0>(b0, af, acc)));
        // Ph4: quadrant (1,1); certify tile 2i+1
        STG_U2(Be, k2);
        asm volatile("s_waitcnt vmcnt(6)" ::: "memory");
        BAR_MFMA((mmq<1, 1>(b1, af, acc)));
        // Ph5: tile 2i+1 quadrant (0,0)
        STG_U3(Ae, k2);
        rdA<0>(Ao, wm, lane16, co0, co1, af);
        rdB<0>(Bo, wn, lane16, co0, co1, b0);
        BAR_MFMA((mmq<0, 0>(b0, af, acc)));
        // Ph6
        STG_U0(Ao, k3);
        rdB<1>(Bo, wn, lane16, co0, co1, b1);
        BAR_MFMA((mmq<0, 1>(b1, af, acc)));
        // Ph7
        STG_U1(Bo, k3);
        rdA<1>(Ao, wm, lane16, co0, co1, af);
        BAR_MFMA((mmq<1, 0>(b0, af, acc)));
        // Ph8: certify tile 2i+2
        STG_U2(Bo, k3);
        asm volatile("s_waitcnt vmcnt(6)" ::: "memory");
        BAR_MFMA((mmq<1, 1>(b1, af, acc)));
    }
    // epilogue: tiles 14 (even bufs) and 15 (odd bufs)
    STG_U3(Ao, 15 * 64);
    rdA<0>(Ae, wm, lane16, co0, co1, af);
    rdB<0>(Be, wn, lane16, co0, co1, b0);
    BAR_MFMA((mmq<0, 0>(b0, af, acc)));
    rdB<1>(Be, wn, lane16, co0, co1, b1);
    BAR_MFMA((mmq<0, 1>(b1, af, acc)));
    rdA<1>(Ae, wm, lane16, co0, co1, af);
    BAR_MFMA((mmq<1, 0>(b0, af, acc)));
    asm volatile("s_waitcnt vmcnt(0)" ::: "memory");   // drain: tile 15 ready
    BAR_MFMA((mmq<1, 1>(b1, af, acc)));
    rdA<0>(Ao, wm, lane16, co0, co1, af);
    rdB<0>(Bo, wn, lane16, co0, co1, b0);
    BAR_MFMA((mmq<0, 0>(b0, af, acc)));
    rdB<1>(Bo, wn, lane16, co0, co1, b1);
    BAR_MFMA((mmq<0, 1>(b1, af, acc)));
    rdA<1>(Ao, wm, lane16, co0, co1, af);
    BAR_MFMA((mmq<1, 0>(b0, af, acc)));
    BAR_MFMA((mmq<1, 1>(b1, af, acc)));
#undef STG_U0
#undef STG_U1
#undef STG_U2
#undef STG_U3
#undef BAR_MFMA
}

// epilogue helper: mode 0 = rope split-head bf16, mode 1 = V^T bf16
static __device__ __forceinline__ void proj_epilogue(
    unsigned short* __restrict__ Out, const float2* __restrict__ cstab,
    int m0, int n0, int mode, floatx4 acc[8][4])
{
    const int t = threadIdx.x;
    const int w = t >> 6, l = t & 63;
    const int wm = w >> 2, wn = w & 3;
    const int lane16 = l & 15, quad = l >> 4;

    if (mode == 0) {
        #pragma unroll
        for (int mi = 0; mi < 8; mi++) {
            int m = m0 + wm * 128 + mi * 16 + lane16;
            int s = m & 511, b = m >> 9;
            #pragma unroll
            for (int ni = 0; ni < 4; ni++) {
                int n = n0 + wn * 64 + ni * 16 + quad * 4;
                int h = n >> 6, d0 = n & 63;
                const float4* cp = (const float4*)&cstab[s * HD + d0];
                float4 c01 = cp[0];   // cos[d0], sin[d0], cos[d0+1], sin[d0+1]
                float4 c23 = cp[1];
                floatx4 v = acc[mi][ni];
                float r0 = v[0] * c01.x - v[1] * c01.y;
                float r1 = fmaf(v[0], c01.w, v[1] * c01.z);
                float r2 = v[2] * c23.x - v[3] * c23.y;
                float r3 = fmaf(v[2], c23.w, v[3] * c23.z);
                uint2 o = { pk2(r0, r1), pk2(r2, r3) };
                *(uint2*)&Out[((size_t)(b * NH + h) * SEQ + s) * HD + d0] = o;
            }
        }
    } else {
        #pragma unroll
        for (int mi = 0; mi < 8; mi++) {
            int m = m0 + wm * 128 + mi * 16 + lane16;   // m = full d index
            #pragma unroll
            for (int ni = 0; ni < 4; ni++) {
                int n = n0 + wn * 64 + ni * 16 + quad * 4;   // flat (b*512+s)
                floatx4 v = acc[mi][ni];
                uint2 o = { pk2(v[0], v[1]), pk2(v[2], v[3]) };
                *(uint2*)&Out[((size_t)(n >> 9) * DIM + m) * SEQ + (n & 511)] = o;
            }
        }
    }
}

// ---------------------------------------------------------------------------
// All three projections in one launch, 384 blocks of 256x256 tiles
// (1 block/CU at 128 KB LDS): [0,128) K+rope, [128,256) V^T, [256,384) Q+rope.
// XCD swizzle: blocks sharing the big-operand strip get ids congruent mod 8
// (same XCD under round-robin) and adjacent in dispatch order.
// ---------------------------------------------------------------------------
__global__ __launch_bounds__(512, 2)
void proj_qkv(const unsigned short* __restrict__ xb, const unsigned short* __restrict__ cb,
              const unsigned short* __restrict__ WqT, const unsigned short* __restrict__ WkT,
              const unsigned short* __restrict__ WvT,
              unsigned short* __restrict__ Qb, unsigned short* __restrict__ Kb,
              unsigned short* __restrict__ Vtb, const float2* __restrict__ cstab)
{
    __shared__ unsigned short As[2 * 256 * 64];   // 64 KB
    __shared__ unsigned short Bs[2 * 256 * 64];   // 64 KB
    const int id = blockIdx.x;
    const int seg = id >> 7, local = id & 127;
    const int big = (local & 7) + (local >> 5) * 8;   // 0..31: strip index
    const int sml = (local >> 3) & 3;                 // 0..3
    const unsigned short *A, *Bt; unsigned short* Out;
    int m0, n0, mode;
    if (seg == 0)      { A = cb;  Bt = WkT; Out = Kb;  mode = 0;   // M=8192,N=1024
                         m0 = big * 256; n0 = sml * 256; }
    else if (seg == 1) { A = WvT; Bt = cb;  Out = Vtb; mode = 1;   // M=1024,N=8192
                         m0 = sml * 256; n0 = big * 256; }
    else               { A = xb;  Bt = WqT; Out = Qb;  mode = 0;   // M=8192,N=1024
                         m0 = big * 256; n0 = sml * 256; }
    floatx4 acc[8][4];
    gemm256(A, Bt, m0, n0, As, Bs, acc);
    proj_epilogue(Out, cstab, m0, n0, mode, acc);
}

// ---------------------------------------------------------------------------
// Output projection: f32 out + bias, float4 stores; 128 blocks.
// ---------------------------------------------------------------------------
__global__ __launch_bounds__(512, 2)
void out_gemm(const unsigned short* __restrict__ Ab, const unsigned short* __restrict__ WoT,
              float* __restrict__ O, const float* __restrict__ bias)
{
    __shared__ unsigned short As[2 * 256 * 64];
    __shared__ unsigned short Bs[2 * 256 * 64];
    const int id = blockIdx.x;
    const int m0 = ((id & 7) + (id >> 5) * 8) * 256;
    const int n0 = ((id >> 3) & 3) * 256;
    floatx4 acc[8][4];
    gemm256(Ab, WoT, m0, n0, As, Bs, acc);

    const int t = threadIdx.x;
    const int w = t >> 6, l = t & 63;
    const int wm = w >> 2, wn = w & 3;
    const int lane16 = l & 15, quad = l >> 4;
    #pragma unroll
    for (int ni = 0; ni < 4; ni++) {
        int n = n0 + wn * 64 + ni * 16 + quad * 4;
        float4 bv = *(const float4*)&bias[n];
        #pragma unroll
        for (int mi = 0; mi < 8; mi++) {
            int m = m0 + wm * 128 + mi * 16 + lane16;
            floatx4 v = acc[mi][ni];
            float4 o = { v[0] + bv.x, v[1] + bv.y, v[2] + bv.z, v[3] + bv.w };
            *(float4*)&O[(size_t)m * DIM + n] = o;
        }
    }
}

// ---------------------------------------------------------------------------
// Flash attention v4 (unchanged, verified): S^T = K·Q^T, in-register P,
// operand-swapped PV, packed 8B stores.
// ---------------------------------------------------------------------------
__global__ __launch_bounds__(256, 4)
void attn_v4(const unsigned short* __restrict__ Q, const unsigned short* __restrict__ K,
             const unsigned short* __restrict__ Vt, unsigned short* __restrict__ Out)
{
    __shared__ unsigned short Qs[128][72];
    __shared__ unsigned short Ks[64][72];
    __shared__ unsigned short Vts[64][72];   // Vts[d][kv_local]

    const int id = blockIdx.x;
    const int qi = (id >> 3) & 3;
    const int bh = (id & 7) | ((id >> 5) << 3);
    const int q0 = qi * 128;
    const int t  = threadIdx.x;
    const int w = t >> 6, l = t & 63;
    const int lane16 = l & 15, quad = l >> 4;
    const size_t base = (size_t)bh * SEQ * HD;

    const int sr = t >> 3, sc = (t & 7) * 8;
    #pragma unroll
    for (int j = 0; j < 4; j++)
        *(uint4*)&Qs[j * 32 + sr][sc] =
            *(const uint4*)&Q[base + (size_t)(q0 + j * 32 + sr) * HD + sc];

    const unsigned short* kp0 = K  + base + (size_t)sr * HD + sc;
    const unsigned short* kp1 = kp0 + (size_t)32 * HD;
    const unsigned short* vp0 = Vt + base + (size_t)sr * SEQ + sc;
    const unsigned short* vp1 = vp0 + (size_t)32 * SEQ;

    floatx4 acc_o[2][4];
    float lsum[2] = {0.f, 0.f};
    #pragma unroll
    for (int st = 0; st < 2; st++)
        #pragma unroll
        for (int dt = 0; dt < 4; dt++) acc_o[st][dt] = (floatx4){0.f, 0.f, 0.f, 0.f};

    for (int kt = 0; kt < SEQ; kt += 64) {
        __syncthreads();
        *(uint4*)&Ks[sr][sc]       = *(const uint4*)kp0;  kp0 += 64 * HD;
        *(uint4*)&Ks[sr + 32][sc]  = *(const uint4*)kp1;  kp1 += 64 * HD;
        *(uint4*)&Vts[sr][sc]      = *(const uint4*)vp0;  vp0 += 64;
        *(uint4*)&Vts[sr + 32][sc] = *(const uint4*)vp1;  vp1 += 64;
        __syncthreads();

        bf16x8 kf[2][4];
        #pragma unroll
        for (int kk = 0; kk < 2; kk++)
            #pragma unroll
            for (int c = 0; c < 4; c++)
                kf[kk][c] = *(const bf16x8*)&Ks[c * 16 + lane16][kk * 32 + quad * 8];

        short4v pa[2][4];
        #pragma unroll
        for (int st = 0; st < 2; st++) {
            floatx4 sacc[4];
            #pragma unroll
            for (int c = 0; c < 4; c++) sacc[c] = (floatx4){0.f, 0.f, 0.f, 0.f};
            #pragma unroll
            for (int kk = 0; kk < 2; kk++) {
                bf16x8 qf = *(const bf16x8*)&Qs[st * 64 + w * 16 + lane16][kk * 32 + quad * 8];
                #pragma unroll
                for (int c = 0; c < 4; c++)
                    sacc[c] = __builtin_amdgcn_mfma_f32_16x16x32_bf16(kf[kk][c], qf, sacc[c], 0, 0, 0);
            }
            #pragma unroll
            for (int c = 0; c < 4; c++) {
                short4v pk;
                #pragma unroll
                for (int i = 0; i < 4; i++) {
                    float pv = exp2f(sacc[c][i] * SL2E);
                    lsum[st] += pv;
                    pk[i] = (short)f2bf(pv);
                }
                pa[st][c] = pk;
            }
        }
        #pragma unroll
        for (int c = 0; c < 4; c++) {
            #pragma unroll
            for (int dt = 0; dt < 4; dt++) {
                short4v vf = *(const short4v*)&Vts[dt * 16 + lane16][c * 16 + quad * 4];
                #pragma unroll
                for (int st = 0; st < 2; st++)
                    acc_o[st][dt] = __builtin_amdgcn_mfma_f32_16x16x16bf16_1k(
                        vf, pa[st][c], acc_o[st][dt], 0, 0, 0);
            }
        }
    }

    const int b = bh >> 4, h = bh & 15;
    #pragma unroll
    for (int st = 0; st < 2; st++) {
        float rs = lsum[st];
        rs += __shfl_xor(rs, 16, 64);
        rs += __shfl_xor(rs, 32, 64);
        float inv = 1.0f / rs;
        int s = q0 + st * 64 + w * 16 + lane16;
        size_t rowbase = (size_t)(b * SEQ + s) * DIM + h * HD;
        #pragma unroll
        for (int dt = 0; dt < 4; dt++) {
            floatx4 v = acc_o[st][dt];
            uint2 o = { pk2(v[0] * inv, v[1] * inv), pk2(v[2] * inv, v[3] * inv) };
            *(uint2*)&Out[rowbase + dt * 16 + quad * 4] = o;
        }
    }
}

// ---------------------------------------------------------------------------
extern "C" void kernel_launch(void* const* d_in, const int* in_sizes, int n_in,
                              void* d_out, int out_size, void* d_ws, size_t ws_size,
                              hipStream_t stream)
{
    const float* x   = (const float*)d_in[0];
    const float* ctx = (const float*)d_in[1];
    const float* Wq  = (const float*)d_in[2];
    const float* Wk  = (const float*)d_in[3];
    const float* Wv  = (const float*)d_in[4];
    const float* Wo  = (const float*)d_in[5];
    const float* bo  = (const float*)d_in[6];

    const size_t NW = (size_t)DIM * DIM;      // 1M elems
    const size_t NB = (size_t)MROWS * DIM;    // 8.4M elems

    unsigned short* x_bf   = (unsigned short*)d_ws;   // 16.8 MB (reused as Ab)
    unsigned short* ctx_bf = x_bf + NB;               // 16.8 MB
    unsigned short* WqT    = ctx_bf + NB;             // 2 MB each
    unsigned short* WkT    = WqT + NW;
    unsigned short* WvT    = WkT + NW;
    unsigned short* WoT    = WvT + NW;
    unsigned short* Kb     = WoT + NW;                // 16.8 MB
    unsigned short* Vtb    = Kb + NB;                 // 16.8 MB
    float2*         cstab  = (float2*)(Vtb + NB);     // 256 KB — total ~75.5 MB
    unsigned short* Qb     = (unsigned short*)d_out;  // scratch: d_out (33.5 MB) holds
                                                      // bf16 Q until out_gemm overwrites
    unsigned short* Ab     = x_bf;                    // alias: x_bf dead after proj_qkv

    prep<<<12416, 256, 0, stream>>>(x, ctx, Wq, Wk, Wv, Wo,
                                    x_bf, ctx_bf, WqT, WkT, WvT, WoT, cstab);

    proj_qkv<<<384, 512, 0, stream>>>(x_bf, ctx_bf, WqT, WkT, WvT,
                                      Qb, Kb, Vtb, cstab);

    attn_v4<<<1024, 256, 0, stream>>>(Qb, Kb, Vtb, Ab);

    out_gemm<<<128, 512, 0, stream>>>(Ab, WoT, (float*)d_out, bo);
}

// Round 4
// 259.170 us; speedup vs baseline: 1.1556x; 1.1556x over previous
//
#include <hip/hip_runtime.h>

#define DIM   1024
#define NH    16
#define HD    64
#define BATCH 16
#define SEQ   512
#define MROWS (BATCH*SEQ)   // 8192
#define SL2E  0.18033688011112042f   // 0.125 * log2(e)

typedef __bf16 bf16x8 __attribute__((ext_vector_type(8)));
typedef float  floatx4 __attribute__((ext_vector_type(4)));
typedef short  short4v __attribute__((ext_vector_type(4)));

static __device__ __forceinline__ unsigned short f2bf(float f) {
    union { float f; unsigned u; } v; v.f = f;
    return (unsigned short)((v.u + 0x8000u) >> 16);
}
static __device__ __forceinline__ unsigned pk2(float a, float b) {
    union { float f; unsigned u; } x, y; x.f = a; y.f = b;
    return ((x.u + 0x8000u) >> 16) | ((y.u + 0x8000u) & 0xffff0000u);
}

static __device__ __forceinline__ void glds16(const void* g, void* l) {
    __builtin_amdgcn_global_load_lds(
        (const __attribute__((address_space(1))) unsigned int*)g,
        (__attribute__((address_space(3))) unsigned int*)l, 16, 0, 0);
}

// ---------------------------------------------------------------------------
// Fused prep: [0,8192) cvt x/ctx -> bf16 ; [8192,12288) transpose 4 weights ;
// [12288,12416) RoPE cos/sin table (interleaved float2 [SEQ][HD], idx d&31).
// ---------------------------------------------------------------------------
__global__ __launch_bounds__(256)
void prep(const float* __restrict__ x, const float* __restrict__ ctx,
          const float* __restrict__ Wq, const float* __restrict__ Wk,
          const float* __restrict__ Wv, const float* __restrict__ Wo,
          unsigned short* __restrict__ xb, unsigned short* __restrict__ cb,
          unsigned short* __restrict__ WqT, unsigned short* __restrict__ WkT,
          unsigned short* __restrict__ WvT, unsigned short* __restrict__ WoT,
          float2* __restrict__ cstab)
{
    __shared__ float tile[32][33];
    const int blk = blockIdx.x, t = threadIdx.x;
    if (blk < 8192) {
        const float* src = (blk < 4096) ? x : ctx;
        unsigned short* dst = (blk < 4096) ? xb : cb;
        int e = ((blk & 4095) * 256 + t) * 8;
        float4 f0 = *(const float4*)&src[e];
        float4 f1 = *(const float4*)&src[e + 4];
        uint4 o = { pk2(f0.x, f0.y), pk2(f0.z, f0.w), pk2(f1.x, f1.y), pk2(f1.z, f1.w) };
        *(uint4*)&dst[e] = o;
    } else if (blk < 12288) {
        int id2 = blk - 8192;
        const float* W; unsigned short* T;
        switch (id2 >> 10) {
            case 0:  W = Wq; T = WqT; break;
            case 1:  W = Wk; T = WkT; break;
            case 2:  W = Wv; T = WvT; break;
            default: W = Wo; T = WoT; break;
        }
        int local = id2 & 1023;
        int n0 = (local & 31) * 32, k0 = (local >> 5) * 32;
        int tx = t & 31, ty = t >> 5;
        #pragma unroll
        for (int a = 0; a < 4; a++)
            tile[ty + 8 * a][tx] = W[(size_t)(k0 + ty + 8 * a) * DIM + n0 + tx];
        __syncthreads();
        #pragma unroll
        for (int a = 0; a < 4; a++)
            T[(size_t)(n0 + ty + 8 * a) * DIM + k0 + tx] = f2bf(tile[tx][ty + 8 * a]);
    } else {
        int gid = (blk - 12288) * 256 + t;   // 0 .. SEQ*HD-1
        int d = gid & (HD - 1), s = gid >> 6;
        const float C = -0.41524101186092f;  // -2*log2(10000)/64
        float f = exp2f((float)(d & 31) * C);
        float a = (float)s * f;
        cstab[gid] = make_float2(cosf(a), sinf(a));
    }
}

// ---------------------------------------------------------------------------
// Shared GEMM main loop (round-0 verified, 78 us): 128x128 tile, BK=64,
// glds16 staging with XOR-swizzled LDS layout (physical 16B chunk p at row r
// holds logical chunk p^(r&7)) — fragment ds_read_b128 <=2-way bank aliasing.
// TRANSPOSED accumulate: acc = mfma(B_frag, A_frag) -> regs hold 4 consecutive n.
// ---------------------------------------------------------------------------
static __device__ __forceinline__ void gemm_main(
    const unsigned short* __restrict__ A, const unsigned short* __restrict__ Bt,
    int m0, int n0, unsigned short* As, unsigned short* Bs, floatx4 acc[4][4])
{
    const int t = threadIdx.x;
    const int w = t >> 6, l = t & 63;
    const int wm = w >> 1, wn = w & 1;
    const int lane16 = l & 15, quad = l >> 4;
    const int lr = l >> 3;
    const int gsw = ((l & 7) ^ lr) * 8;          // swizzled source col (shorts)
    const int co0 = (quad ^ (lane16 & 7)) * 8;   // fragment chunk offset, kk=0
    const int co1 = co0 ^ 32;                    // kk=1 (^4 chunks = ^32 shorts)

    #pragma unroll
    for (int mi = 0; mi < 4; mi++)
        #pragma unroll
        for (int ni = 0; ni < 4; ni++) acc[mi][ni] = (floatx4){0.f, 0.f, 0.f, 0.f};

    const unsigned short* ap = A  + (size_t)(m0 + w * 32 + lr) * DIM + gsw;
    const unsigned short* bp = Bt + (size_t)(n0 + w * 32 + lr) * DIM + gsw;

    for (int kt = 0; kt < DIM; kt += 64) {
        #pragma unroll
        for (int j = 0; j < 4; j++) {
            glds16(ap + (size_t)j * 8 * DIM + kt, &As[(w * 4 + j) * 512]);
            glds16(bp + (size_t)j * 8 * DIM + kt, &Bs[(w * 4 + j) * 512]);
        }
        __syncthreads();
        #pragma unroll
        for (int kk = 0; kk < 2; kk++) {
            const int co = kk ? co1 : co0;
            bf16x8 af[4], bfr[4];
            #pragma unroll
            for (int mi = 0; mi < 4; mi++)
                af[mi] = *(const bf16x8*)&As[(wm * 64 + mi * 16 + lane16) * 64 + co];
            #pragma unroll
            for (int ni = 0; ni < 4; ni++)
                bfr[ni] = *(const bf16x8*)&Bs[(wn * 64 + ni * 16 + lane16) * 64 + co];
            #pragma unroll
            for (int mi = 0; mi < 4; mi++)
                #pragma unroll
                for (int ni = 0; ni < 4; ni++)
                    acc[mi][ni] = __builtin_amdgcn_mfma_f32_16x16x32_bf16(bfr[ni], af[mi], acc[mi][ni], 0, 0, 0);
        }
        __syncthreads();
    }
}

// epilogue helper: mode 0 = rope split-head bf16, mode 1 = V^T bf16
static __device__ __forceinline__ void proj_epilogue(
    unsigned short* __restrict__ Out, const float2* __restrict__ cstab,
    int m0, int n0, int mode, floatx4 acc[4][4])
{
    const int t = threadIdx.x;
    const int w = t >> 6, l = t & 63;
    const int wm = w >> 1, wn = w & 1;
    const int lane16 = l & 15, quad = l >> 4;

    if (mode == 0) {
        #pragma unroll
        for (int mi = 0; mi < 4; mi++) {
            int m = m0 + wm * 64 + mi * 16 + lane16;
            int s = m & 511, b = m >> 9;
            #pragma unroll
            for (int ni = 0; ni < 4; ni++) {
                int n = n0 + wn * 64 + ni * 16 + quad * 4;
                int h = n >> 6, d0 = n & 63;
                const float4* cp = (const float4*)&cstab[s * HD + d0];
                float4 c01 = cp[0];   // cos[d0], sin[d0], cos[d0+1], sin[d0+1]
                float4 c23 = cp[1];
                floatx4 v = acc[mi][ni];
                float r0 = v[0] * c01.x - v[1] * c01.y;
                float r1 = fmaf(v[0], c01.w, v[1] * c01.z);
                float r2 = v[2] * c23.x - v[3] * c23.y;
                float r3 = fmaf(v[2], c23.w, v[3] * c23.z);
                uint2 o = { pk2(r0, r1), pk2(r2, r3) };
                *(uint2*)&Out[((size_t)(b * NH + h) * SEQ + s) * HD + d0] = o;
            }
        }
    } else {
        #pragma unroll
        for (int mi = 0; mi < 4; mi++) {
            int m = m0 + wm * 64 + mi * 16 + lane16;   // m = full d index
            #pragma unroll
            for (int ni = 0; ni < 4; ni++) {
                int n = n0 + wn * 64 + ni * 16 + quad * 4;   // flat (b*512+s)
                floatx4 v = acc[mi][ni];
                uint2 o = { pk2(v[0], v[1]), pk2(v[2], v[3]) };
                *(uint2*)&Out[((size_t)(n >> 9) * DIM + m) * SEQ + (n & 511)] = o;
            }
        }
    }
}

// ---------------------------------------------------------------------------
// All three projections in one launch, 1536 blocks:
// [0,512) K+rope, [512,1024) V^T, [1024,1536) Q+rope.
// Per-512 grid swizzle: the 8 blocks sharing an A-strip get id = same (mod 8)
// (same XCD under round-robin) and adjacent dispatch order.
// ---------------------------------------------------------------------------
__global__ __launch_bounds__(256)
void proj_qkv(const unsigned short* __restrict__ xb, const unsigned short* __restrict__ cb,
              const unsigned short* __restrict__ WqT, const unsigned short* __restrict__ WkT,
              const unsigned short* __restrict__ WvT,
              unsigned short* __restrict__ Qb, unsigned short* __restrict__ Kb,
              unsigned short* __restrict__ Vtb, const float2* __restrict__ cstab)
{
    __shared__ unsigned short As[128 * 64];
    __shared__ unsigned short Bs[128 * 64];
    const int id = blockIdx.x;
    const int seg = id >> 9, local = id & 511;
    const int xcd = local & 7, seq = local >> 3;
    const unsigned short *A, *Bt; unsigned short* Out;
    int m0, n0, mode;
    if (seg == 0)      { A = cb;  Bt = WkT; Out = Kb;  mode = 0;
                         n0 = (seq & 7) * 128; m0 = (xcd + 8 * (seq >> 3)) * 128; }
    else if (seg == 1) { A = WvT; Bt = cb;  Out = Vtb; mode = 1;
                         m0 = (seq & 7) * 128; n0 = (xcd + 8 * (seq >> 3)) * 128; }
    else               { A = xb;  Bt = WqT; Out = Qb;  mode = 0;
                         n0 = (seq & 7) * 128; m0 = (xcd + 8 * (seq >> 3)) * 128; }
    floatx4 acc[4][4];
    gemm_main(A, Bt, m0, n0, As, Bs, acc);
    proj_epilogue(Out, cstab, m0, n0, mode, acc);
}

// ---------------------------------------------------------------------------
// Output projection: f32 out + bias, float4 stores; same grid swizzle.
// ---------------------------------------------------------------------------
__global__ __launch_bounds__(256)
void out_gemm(const unsigned short* __restrict__ Ab, const unsigned short* __restrict__ WoT,
              float* __restrict__ O, const float* __restrict__ bias)
{
    __shared__ unsigned short As[128 * 64];
    __shared__ unsigned short Bs[128 * 64];
    const int id = blockIdx.x;
    const int xcd = id & 7, seq = id >> 3;
    const int n0 = (seq & 7) * 128, m0 = (xcd + 8 * (seq >> 3)) * 128;
    floatx4 acc[4][4];
    gemm_main(Ab, WoT, m0, n0, As, Bs, acc);

    const int t = threadIdx.x;
    const int w = t >> 6, l = t & 63;
    const int wm = w >> 1, wn = w & 1;
    const int lane16 = l & 15, quad = l >> 4;
    #pragma unroll
    for (int ni = 0; ni < 4; ni++) {
        int n = n0 + wn * 64 + ni * 16 + quad * 4;
        float4 bv = *(const float4*)&bias[n];
        #pragma unroll
        for (int mi = 0; mi < 4; mi++) {
            int m = m0 + wm * 64 + mi * 16 + lane16;
            floatx4 v = acc[mi][ni];
            float4 o = { v[0] + bv.x, v[1] + bv.y, v[2] + bv.z, v[3] + bv.w };
            *(float4*)&O[(size_t)m * DIM + n] = o;
        }
    }
}

// ---------------------------------------------------------------------------
// Flash attention v5: round-0 v4 + T14 async-STAGE split.
// K/V tile t+1 prefetched into registers BEFORE tile t's compute; stored to
// LDS at top of next iteration. Raw s_barrier (no vmcnt drain) + per-thread
// lgkmcnt(0) before the release barrier. Prefetch loads ride across both
// barriers and land under ~40 MFMA + softmax of compute (T14, +17% evidence).
// ---------------------------------------------------------------------------
__global__ __launch_bounds__(256, 4)
void attn_v4(const unsigned short* __restrict__ Q, const unsigned short* __restrict__ K,
             const unsigned short* __restrict__ Vt, unsigned short* __restrict__ Out)
{
    __shared__ unsigned short Qs[128][72];
    __shared__ unsigned short Ks[64][72];
    __shared__ unsigned short Vts[64][72];   // Vts[d][kv_local]

    const int id = blockIdx.x;
    const int qi = (id >> 3) & 3;
    const int bh = (id & 7) | ((id >> 5) << 3);
    const int q0 = qi * 128;
    const int t  = threadIdx.x;
    const int w = t >> 6, l = t & 63;
    const int lane16 = l & 15, quad = l >> 4;
    const size_t base = (size_t)bh * SEQ * HD;

    const int sr = t >> 3, sc = (t & 7) * 8;
    #pragma unroll
    for (int j = 0; j < 4; j++)
        *(uint4*)&Qs[j * 32 + sr][sc] =
            *(const uint4*)&Q[base + (size_t)(q0 + j * 32 + sr) * HD + sc];

    const unsigned short* kp0 = K  + base + (size_t)sr * HD + sc;
    const unsigned short* kp1 = kp0 + (size_t)32 * HD;
    const unsigned short* vp0 = Vt + base + (size_t)sr * SEQ + sc;
    const unsigned short* vp1 = vp0 + (size_t)32 * SEQ;

    // T14 prologue: tile 0 K/V into registers
    uint4 kr0 = *(const uint4*)kp0;  kp0 += (size_t)64 * HD;
    uint4 kr1 = *(const uint4*)kp1;  kp1 += (size_t)64 * HD;
    uint4 vr0 = *(const uint4*)vp0;  vp0 += 64;
    uint4 vr1 = *(const uint4*)vp1;  vp1 += 64;

    floatx4 acc_o[2][4];
    float lsum[2] = {0.f, 0.f};
    #pragma unroll
    for (int st = 0; st < 2; st++)
        #pragma unroll
        for (int dt = 0; dt < 4; dt++) acc_o[st][dt] = (floatx4){0.f, 0.f, 0.f, 0.f};

    for (int kt = 0; kt < SEQ; kt += 64) {
        __builtin_amdgcn_s_barrier();          // WAR: prev tile's LDS reads done (raw — vmcnt rides)
        *(uint4*)&Ks[sr][sc]       = kr0;
        *(uint4*)&Ks[sr + 32][sc]  = kr1;
        *(uint4*)&Vts[sr][sc]      = vr0;
        *(uint4*)&Vts[sr + 32][sc] = vr1;
        if (kt + 64 < SEQ) {                   // issue next-tile loads; hide under compute
            kr0 = *(const uint4*)kp0;  kp0 += (size_t)64 * HD;
            kr1 = *(const uint4*)kp1;  kp1 += (size_t)64 * HD;
            vr0 = *(const uint4*)vp0;  vp0 += 64;
            vr1 = *(const uint4*)vp1;  vp1 += 64;
        }
        asm volatile("s_waitcnt lgkmcnt(0)" ::: "memory");   // own ds_writes drained
        __builtin_amdgcn_s_barrier();          // all stores visible
        bf16x8 kf[2][4];
        #pragma unroll
        for (int kk = 0; kk < 2; kk++)
            #pragma unroll
            for (int c = 0; c < 4; c++)
                kf[kk][c] = *(const bf16x8*)&Ks[c * 16 + lane16][kk * 32 + quad * 8];

        short4v pa[2][4];
        #pragma unroll
        for (int st = 0; st < 2; st++) {
            floatx4 sacc[4];
            #pragma unroll
            for (int c = 0; c < 4; c++) sacc[c] = (floatx4){0.f, 0.f, 0.f, 0.f};
            #pragma unroll
            for (int kk = 0; kk < 2; kk++) {
                bf16x8 qf = *(const bf16x8*)&Qs[st * 64 + w * 16 + lane16][kk * 32 + quad * 8];
                #pragma unroll
                for (int c = 0; c < 4; c++)
                    sacc[c] = __builtin_amdgcn_mfma_f32_16x16x32_bf16(kf[kk][c], qf, sacc[c], 0, 0, 0);
            }
            #pragma unroll
            for (int c = 0; c < 4; c++) {
                short4v pk;
                #pragma unroll
                for (int i = 0; i < 4; i++) {
                    float pv = exp2f(sacc[c][i] * SL2E);
                    lsum[st] += pv;
                    pk[i] = (short)f2bf(pv);
                }
                pa[st][c] = pk;
            }
        }
        #pragma unroll
        for (int c = 0; c < 4; c++) {
            #pragma unroll
            for (int dt = 0; dt < 4; dt++) {
                short4v vf = *(const short4v*)&Vts[dt * 16 + lane16][c * 16 + quad * 4];
                #pragma unroll
                for (int st = 0; st < 2; st++)
                    acc_o[st][dt] = __builtin_amdgcn_mfma_f32_16x16x16bf16_1k(
                        vf, pa[st][c], acc_o[st][dt], 0, 0, 0);
            }
        }
    }

    const int b = bh >> 4, h = bh & 15;
    #pragma unroll
    for (int st = 0; st < 2; st++) {
        float rs = lsum[st];
        rs += __shfl_xor(rs, 16, 64);
        rs += __shfl_xor(rs, 32, 64);
        float inv = 1.0f / rs;
        int s = q0 + st * 64 + w * 16 + lane16;
        size_t rowbase = (size_t)(b * SEQ + s) * DIM + h * HD;
        #pragma unroll
        for (int dt = 0; dt < 4; dt++) {
            floatx4 v = acc_o[st][dt];
            uint2 o = { pk2(v[0] * inv, v[1] * inv), pk2(v[2] * inv, v[3] * inv) };
            *(uint2*)&Out[rowbase + dt * 16 + quad * 4] = o;
        }
    }
}

// ---------------------------------------------------------------------------
extern "C" void kernel_launch(void* const* d_in, const int* in_sizes, int n_in,
                              void* d_out, int out_size, void* d_ws, size_t ws_size,
                              hipStream_t stream)
{
    const float* x   = (const float*)d_in[0];
    const float* ctx = (const float*)d_in[1];
    const float* Wq  = (const float*)d_in[2];
    const float* Wk  = (const float*)d_in[3];
    const float* Wv  = (const float*)d_in[4];
    const float* Wo  = (const float*)d_in[5];
    const float* bo  = (const float*)d_in[6];

    const size_t NW = (size_t)DIM * DIM;      // 1M elems
    const size_t NB = (size_t)MROWS * DIM;    // 8.4M elems

    unsigned short* x_bf   = (unsigned short*)d_ws;   // 16.8 MB (reused as Ab)
    unsigned short* ctx_bf = x_bf + NB;               // 16.8 MB
    unsigned short* WqT    = ctx_bf + NB;             // 2 MB each
    unsigned short* WkT    = WqT + NW;
    unsigned short* WvT    = WkT + NW;
    unsigned short* WoT    = WvT + NW;
    unsigned short* Kb     = WoT + NW;                // 16.8 MB
    unsigned short* Vtb    = Kb + NB;                 // 16.8 MB
    float2*         cstab  = (float2*)(Vtb + NB);     // 256 KB — total ~75.5 MB
    unsigned short* Qb     = (unsigned short*)d_out;  // scratch: d_out (33.5 MB) holds
                                                      // bf16 Q until out_gemm overwrites
    unsigned short* Ab     = x_bf;                    // alias: x_bf dead after proj_qkv

    prep<<<12416, 256, 0, stream>>>(x, ctx, Wq, Wk, Wv, Wo,
                                    x_bf, ctx_bf, WqT, WkT, WvT, WoT, cstab);

    proj_qkv<<<1536, 256, 0, stream>>>(x_bf, ctx_bf, WqT, WkT, WvT,
                                       Qb, Kb, Vtb, cstab);

    attn_v4<<<1024, 256, 0, stream>>>(Qb, Kb, Vtb, Ab);

    out_gemm<<<512, 256, 0, stream>>>(Ab, WoT, (float*)d_out, bo);
}